// Round 14
// baseline (201.916 us; speedup 1.0000x reference)
//
#include <hip/hip_runtime.h>
#include <math.h>

#define B_ 2
#define C_ 4
#define N_ 224
#define V_ 7
#define W_ 256
#define S_ 1792
#define EMB_ 256
#define H_ 4
#define D_ 64
#define TOK_ 896
#define HF_ 10
#define JC_ 8
#define JRANGE_ (S_ / JC_)      /* 224 */
#define JSTEPS_ (JRANGE_ / 32)  /* 7 */

typedef __attribute__((ext_vector_type(8))) short short8;
typedef __attribute__((ext_vector_type(4))) float f32x4;

#define MFMA16(a, b, c) __builtin_amdgcn_mfma_f32_16x16x32_bf16(a, b, c, 0, 0, 0)

__device__ inline short f2bf(float f) {
    union { float f; unsigned u; } x; x.f = f;
    unsigned u = x.u;
    unsigned r = (u + 0x7fffu + ((u >> 16) & 1u)) >> 16;
    return (short)r;
}
__device__ inline float bf2f(short s) {
    union { unsigned u; float f; } x;
    x.u = ((unsigned)(unsigned short)s) << 16;
    return x.f;
}
// pack two f32 -> one dword of 2 bf16 (RNE), single instruction on gfx950
__device__ inline unsigned cvtpk_bf16(float lo, float hi) {
    unsigned r;
    asm("v_cvt_pk_bf16_f32 %0, %1, %2" : "=v"(r) : "v"(lo), "v"(hi));
    return r;
}

// ---- 64M x 128N x 32K bf16 MFMA GEMM, XOR-swizzled LDS ----
template<bool COLSUM, bool LNB, bool BBF>
__global__ __launch_bounds__(256) void gemm_kernel(
    const float* __restrict__ A, const void* __restrict__ Bv, float* __restrict__ Cm,
    int M, int N, int K, long b_bs, long c_bs,
    const float* __restrict__ csin, float* __restrict__ csout,
    const float* __restrict__ lg, const float* __restrict__ lb)
{
    const int bz = blockIdx.z;
    Cm += (long)bz * c_bs;
    const int m0 = blockIdx.y * 64, n0 = blockIdx.x * 128;
    __shared__ __align__(16) short As[64 * 32];
    __shared__ __align__(16) short Bs[128 * 32];
    const int t = threadIdx.x;
    const int lane = t & 63, wave = t >> 6;
    const int wr = wave >> 1, wc = wave & 1;
    const int col = lane & 15, grp = lane >> 4;
    const int arow = t >> 2, akc = (t & 3) * 8;
    const int bn = t & 127, bkc = (t >> 7) * 16;
    float mean = 0.f, rstd = 1.f;
    if (LNB) {
        float s = 0.f, q = 0.f;
        #pragma unroll
        for (int mb = 0; mb < 4; ++mb) {
            s += csin[((long)(bz * 4 + mb) * 2 + 0) * N + n0 + bn];
            q += csin[((long)(bz * 4 + mb) * 2 + 1) * N + n0 + bn];
        }
        mean = s * (1.f / 256.f);
        rstd = rsqrtf(q * (1.f / 256.f) - mean * mean + 1e-6f);
    }
    f32x4 acc[2][4];
    #pragma unroll
    for (int i = 0; i < 2; ++i)
        #pragma unroll
        for (int j = 0; j < 4; ++j) acc[i][j] = (f32x4){0.f, 0.f, 0.f, 0.f};
    for (int k0 = 0; k0 < K; k0 += 32) {
        {
            const float* ap = &A[(long)(m0 + arow) * K + k0 + akc];
            f32x4 a0 = *(const f32x4*)ap;
            f32x4 a1 = *(const f32x4*)(ap + 4);
            short8 av;
            av[0] = f2bf(a0[0]); av[1] = f2bf(a0[1]); av[2] = f2bf(a0[2]); av[3] = f2bf(a0[3]);
            av[4] = f2bf(a1[0]); av[5] = f2bf(a1[1]); av[6] = f2bf(a1[2]); av[7] = f2bf(a1[3]);
            int abyte = (arow << 6) + (akc << 1);
            *(short8*)((char*)As + (abyte ^ ((arow & 7) << 4))) = av;
        }
        {
            short8 b0, b1;
            if (BBF) {
                const short* Bp = (const short*)Bv + (long)bz * b_bs;
                #pragma unroll
                for (int j = 0; j < 8; ++j) {
                    b0[j] = Bp[(long)(k0 + bkc + j) * N + n0 + bn];
                    b1[j] = Bp[(long)(k0 + bkc + 8 + j) * N + n0 + bn];
                }
            } else {
                const float* Bp = (const float*)Bv + (long)bz * b_bs;
                #pragma unroll
                for (int j = 0; j < 16; ++j) {
                    float v = Bp[(long)(k0 + bkc + j) * N + n0 + bn];
                    if (LNB) v = fmaf((v - mean) * rstd, lg[k0 + bkc + j], lb[k0 + bkc + j]);
                    if (j < 8) b0[j] = f2bf(v); else b1[j - 8] = f2bf(v);
                }
            }
            int bbyte = (bn << 6) + (bkc << 1);
            *(short8*)((char*)Bs + ((bbyte) ^ ((bn & 7) << 4))) = b0;
            *(short8*)((char*)Bs + ((bbyte + 16) ^ ((bn & 7) << 4))) = b1;
        }
        __syncthreads();
        short8 af[2], bfv[4];
        #pragma unroll
        for (int mm = 0; mm < 2; ++mm) {
            int r = wr * 32 + mm * 16 + col;
            af[mm] = *(const short8*)((const char*)As + (((r << 6) + (grp << 4)) ^ ((r & 7) << 4)));
        }
        #pragma unroll
        for (int nn = 0; nn < 4; ++nn) {
            int r = wc * 64 + nn * 16 + col;
            bfv[nn] = *(const short8*)((const char*)Bs + (((r << 6) + (grp << 4)) ^ ((r & 7) << 4)));
        }
        #pragma unroll
        for (int mm = 0; mm < 2; ++mm)
            #pragma unroll
            for (int nn = 0; nn < 4; ++nn)
                acc[mm][nn] = MFMA16(af[mm], bfv[nn], acc[mm][nn]);
        __syncthreads();
    }
    #pragma unroll
    for (int mm = 0; mm < 2; ++mm)
        #pragma unroll
        for (int nn = 0; nn < 4; ++nn)
            #pragma unroll
            for (int r = 0; r < 4; ++r)
                Cm[(long)(m0 + wr * 32 + mm * 16 + grp * 4 + r) * N
                   + n0 + wc * 64 + nn * 16 + col] = acc[mm][nn][r];
    if (COLSUM) {
        float* red = (float*)As;
        #pragma unroll
        for (int nn = 0; nn < 4; ++nn) {
            float s = 0.f, q = 0.f;
            #pragma unroll
            for (int mm = 0; mm < 2; ++mm)
                #pragma unroll
                for (int r = 0; r < 4; ++r) { float v = acc[mm][nn][r]; s += v; q += v * v; }
            s += __shfl_xor(s, 16, 64); s += __shfl_xor(s, 32, 64);
            q += __shfl_xor(q, 16, 64); q += __shfl_xor(q, 32, 64);
            if (lane < 16) {
                int cidx = wc * 64 + nn * 16 + col;
                red[(wr * 128 + cidx) * 2]     = s;
                red[(wr * 128 + cidx) * 2 + 1] = q;
            }
        }
        __syncthreads();
        if (wave < 2 && lane < 16) {
            #pragma unroll
            for (int nn = 0; nn < 4; ++nn) {
                int cidx = wc * 64 + nn * 16 + col;
                float s = red[cidx * 2]     + red[(128 + cidx) * 2];
                float q = red[cidx * 2 + 1] + red[(128 + cidx) * 2 + 1];
                csout[((long)(bz * 4 + blockIdx.y) * 2 + 0) * N + n0 + cidx] = s;
                csout[((long)(bz * 4 + blockIdx.y) * 2 + 1) * N + n0 + cidx] = q;
            }
        }
    }
}

// ------- depthwise 3x3, SAME; V channels (512..767) also emitted as bf16 [b][256][S] -------
__global__ void dwconv3_kernel(const float* __restrict__ X, const float* __restrict__ Wt,
                               float* __restrict__ Y, short* __restrict__ vbf,
                               long total, int Ch)
{
    long idx = (long)blockIdx.x * blockDim.x + threadIdx.x;
    long stride = (long)gridDim.x * blockDim.x;
    for (; idx < total; idx += stride) {
        int w = (int)(idx % W_);
        long t = idx / W_;
        int h = (int)(t % V_); t /= V_;
        int ch = (int)(t % Ch);
        long img_ch = idx / ((long)V_ * W_);
        const float* wp = Wt + ch * 9;
        const float* xp = X + img_ch * (V_ * W_);
        float acc = 0.f;
        #pragma unroll
        for (int dy = -1; dy <= 1; ++dy) {
            int h2 = h + dy;
            if (h2 < 0 || h2 >= V_) continue;
            #pragma unroll
            for (int dx = -1; dx <= 1; ++dx) {
                int w2 = w + dx;
                if (w2 < 0 || w2 >= W_) continue;
                acc += xp[h2 * W_ + w2] * wp[(dy + 1) * 3 + (dx + 1)];
            }
        }
        Y[idx] = acc;
        if (vbf && ch >= 512) {
            int b = (int)(t / Ch);
            vbf[((long)b * 256 + (ch - 512)) * S_ + h * W_ + w] = f2bf(acc);
        }
    }
}

// ------- head transpose + L2-normalize -> bf16 [B][H][S][64]; q also scaled by temp -------
__global__ __launch_bounds__(256) void headnorm_kernel(
    const float* __restrict__ qkvd, const float* __restrict__ temp,
    short* __restrict__ qn, short* __restrict__ kn)
{
    int s0 = blockIdx.x * 64;
    int bh = blockIdx.y; int b = bh >> 2, h = bh & 3;
    int isq = blockIdx.z;                    // 0 = k, 1 = q
    int ch0 = b * 768 + (isq ? 0 : EMB_) + h * 64;
    short* dst = (isq ? qn : kn) + (long)bh * S_ * 64;
    __shared__ float tile[64][65];
    __shared__ float red[64][4];
    int t = threadIdx.x;
    int sl = t & 63, dg = t >> 6;
    float part = 0.f;
    for (int dd = 0; dd < 16; ++dd) {
        int d = dg * 16 + dd;
        float v = qkvd[(long)(ch0 + d) * S_ + s0 + sl];
        tile[sl][d] = v;
        part += v * v;
    }
    red[sl][dg] = part;
    __syncthreads();
    int d = t & 63, sg = t >> 6;
    float tmul = isq ? temp[h] : 1.f;
    for (int si = 0; si < 16; ++si) {
        int s = sg * 16 + si;
        float nrm = sqrtf(red[s][0] + red[s][1] + red[s][2] + red[s][3]);
        float scale = tmul / fmaxf(nrm, 1e-12f);
        dst[(long)(s0 + s) * 64 + d] = f2bf(tile[s][d] * scale);
    }
}

// --- fused attention, swapped-QK; dbuf bf16 exchange (17KB LDS); pipelined K/V; cvt_pk ---
__global__ __launch_bounds__(256) void attn_kernel(
    const short* __restrict__ qn, const short* __restrict__ kn,
    const short* __restrict__ vbf, const float* __restrict__ wat,
    short* __restrict__ partY, float* __restrict__ partZ)
{
    const int h = threadIdx.x >> 6;           // wave = head
    const int lane = threadIdx.x & 63;
    const int col = lane & 15, grp = lane >> 4;
    const int itile = blockIdx.x;             // 0..111
    const int jc = blockIdx.y;                // 0..JC_-1
    const int b = blockIdx.z;
    const int ibase = itile * 16;
    const int bh = b * 4 + h;

    const short* qrow = qn + ((long)bh * S_ + ibase + col) * 64 + grp * 8;
    short8 qa0 = *(const short8*)qrow;
    short8 qa1 = *(const short8*)(qrow + 32);
    float wsc[4], wsh[4];
    #pragma unroll
    for (int hh = 0; hh < 4; ++hh) { wsc[hh] = wat[h * 4 + hh]; wsh[hh] = wat[(4 + h) * 4 + hh]; }

    __shared__ short exch[2][4][32][34];      // bf16 a1 exchange: 17,408 B total

    f32x4 y1[4], y2[4];
    #pragma unroll
    for (int dt = 0; dt < 4; ++dt) {
        y1[dt] = (f32x4){0.f, 0.f, 0.f, 0.f};
        y2[dt] = (f32x4){0.f, 0.f, 0.f, 0.f};
    }
    float z = 0.f;
    const short* kbase = kn + (long)bh * S_ * 64;
    const short* vbase = vbf + ((long)b * 256 + h * 64) * S_;
    const int joffA = (col & 3) + 8 * (col >> 2);   // permuted j for A(M)-rows
    const int jbase0 = jc * JRANGE_;

    // prefetch step 0 K/V rows
    short8 kc0, kc1, kc2, kc3, vc0, vc1, vc2, vc3;
    {
        const short* kr0 = kbase + (long)(jbase0 + joffA) * 64 + grp * 8;
        const short* kr1 = kbase + (long)(jbase0 + joffA + 4) * 64 + grp * 8;
        kc0 = *(const short8*)kr0; kc1 = *(const short8*)(kr0 + 32);
        kc2 = *(const short8*)kr1; kc3 = *(const short8*)(kr1 + 32);
        const short* vr = vbase + (long)col * S_ + jbase0 + grp * 8;
        vc0 = *(const short8*)vr;
        vc1 = *(const short8*)(vr + 16 * S_);
        vc2 = *(const short8*)(vr + 32 * S_);
        vc3 = *(const short8*)(vr + 48 * S_);
    }

    for (int jt = 0; jt < JSTEPS_; ++jt) {
        const int jbase = jbase0 + jt * 32;
        const int buf = jt & 1;
        // prefetch next step (issued before compute+barrier; barrier drain completes them)
        short8 kp0, kp1, kp2, kp3, vp0, vp1, vp2, vp3;
        if (jt + 1 < JSTEPS_) {
            const int jb2 = jbase + 32;
            const short* kr0 = kbase + (long)(jb2 + joffA) * 64 + grp * 8;
            const short* kr1 = kbase + (long)(jb2 + joffA + 4) * 64 + grp * 8;
            kp0 = *(const short8*)kr0; kp1 = *(const short8*)(kr0 + 32);
            kp2 = *(const short8*)kr1; kp3 = *(const short8*)(kr1 + 32);
            const short* vr = vbase + (long)col * S_ + jb2 + grp * 8;
            vp0 = *(const short8*)vr;
            vp1 = *(const short8*)(vr + 16 * S_);
            vp2 = *(const short8*)(vr + 32 * S_);
            vp3 = *(const short8*)(vr + 48 * S_);
        } else {
            kp0 = kc0; kp1 = kc1; kp2 = kc2; kp3 = kc3;
            vp0 = vc0; vp1 = vc1; vp2 = vc2; vp3 = vc3;
        }
        f32x4 lf[2];
        {
            f32x4 a = (f32x4){0.f, 0.f, 0.f, 0.f};
            a = MFMA16(kc0, qa0, a);
            a = MFMA16(kc1, qa1, a);
            lf[0] = a;
        }
        {
            f32x4 a = (f32x4){0.f, 0.f, 0.f, 0.f};
            a = MFMA16(kc2, qa0, a);
            a = MFMA16(kc3, qa1, a);
            lf[1] = a;   // reg r: L[j = jbase + 8*grp + 4*tt + r][i = ibase+col]
        }
        float a1own[2][4], ee[2][4];
        #pragma unroll
        for (int tt = 0; tt < 2; ++tt)
            #pragma unroll
            for (int r = 0; r < 4; ++r) {
                float l = lf[tt][r];
                float rr = fmaxf(l, 0.f);
                float s1 = rr * rr;
                float u = fmaf(s1 * s1, 0.0713548162726f * s1, 1.59576912161f * s1);
                float sg = __builtin_amdgcn_rcpf(1.f + __expf(-u));
                float a1 = s1 * sg * s1;
                a1own[tt][r] = a1;
                ee[tt][r] = __expf(l);
                exch[buf][h][r + 4 * tt + 8 * grp][col] = f2bf(a1);
            }
        __syncthreads();
        union { short8 s; unsigned u[4]; } pa_, pb_;
        #pragma unroll
        for (int tt = 0; tt < 2; ++tt) {
            float scv[4], shv[4];
            #pragma unroll
            for (int r = 0; r < 4; ++r) {
                int jloc = r + 4 * tt + 8 * grp;
                float sc = 0.f, sh = 0.f;
                #pragma unroll
                for (int hh = 0; hh < 4; ++hh) {
                    float a1v = (hh == h) ? a1own[tt][r] : bf2f(exch[buf][hh][jloc][col]);
                    sc += a1v * wsc[hh];
                    sh += a1v * wsh[hh];
                }
                float e = ee[tt][r];
                z += e;
                scv[r] = e * (1.f + sc);
                shv[r] = sh;
            }
            pa_.u[tt * 2]     = cvtpk_bf16(scv[0], scv[1]);
            pa_.u[tt * 2 + 1] = cvtpk_bf16(scv[2], scv[3]);
            pb_.u[tt * 2]     = cvtpk_bf16(shv[0], shv[1]);
            pb_.u[tt * 2 + 1] = cvtpk_bf16(shv[2], shv[3]);
        }
        // no second barrier: next iteration writes the other exch buffer
        y1[0] = MFMA16(pa_.s, vc0, y1[0]); y2[0] = MFMA16(pb_.s, vc0, y2[0]);
        y1[1] = MFMA16(pa_.s, vc1, y1[1]); y2[1] = MFMA16(pb_.s, vc1, y2[1]);
        y1[2] = MFMA16(pa_.s, vc2, y1[2]); y2[2] = MFMA16(pb_.s, vc2, y2[2]);
        y1[3] = MFMA16(pa_.s, vc3, y1[3]); y2[3] = MFMA16(pb_.s, vc3, y2[3]);
        // rotate pipeline registers
        kc0 = kp0; kc1 = kp1; kc2 = kp2; kc3 = kp3;
        vc0 = vp0; vc1 = vp1; vc2 = vp2; vc3 = vp3;
    }

    // Z: reduce over grp replicas for i = ibase+col
    z += __shfl_xor(z, 16, 64);
    z += __shfl_xor(z, 32, 64);
    if (grp == 0)
        partZ[((long)(jc * 2 + b) * 4 + h) * S_ + ibase + col] = z;

    // epilogue: transpose Y frags via wave-private bf16 LDS, write [d][i] coalesced over i
    __syncthreads();
    short* tbs = &exch[0][h][0][0];   // 1088 shorts per head region, 272 used (16x17)
    long ybase = ((((long)jc * 2 + b) * 4 + h) * 2) * 64 * S_;
    for (int acc = 0; acc < 2; ++acc) {
        #pragma unroll
        for (int dt = 0; dt < 4; ++dt) {
            f32x4 y = acc ? y2[dt] : y1[dt];
            #pragma unroll
            for (int r = 0; r < 4; ++r) tbs[(grp * 4 + r) * 17 + col] = f2bf(y[r]);
            #pragma unroll
            for (int p = 0; p < 4; ++p) {
                short val = tbs[col * 17 + p * 4 + grp];
                partY[ybase + ((long)acc * 64 + dt * 16 + p * 4 + grp) * S_ + ibase + col] = val;
            }
        }
    }
}

// ---------------- combine j-chunks: outav = (sum Y1)/(sum Z) + sum Y2, bf16 ----------------
__global__ __launch_bounds__(256) void combine_kernel(
    const short* __restrict__ partY, const float* __restrict__ partZ,
    short* __restrict__ outav)
{
    int idx = blockIdx.x * 256 + threadIdx.x;
    int i = idx % S_;
    int t = idx / S_;
    int d = t & 63; t >>= 6;
    int h = t & 3; int b = t >> 2;
    float y1 = 0.f, y2 = 0.f, z = 0.f;
    #pragma unroll
    for (int jc = 0; jc < JC_; ++jc) {
        long base = ((((long)jc * 2 + b) * 4 + h) * 2) * 64 * S_;
        y1 += bf2f(partY[base + (long)d * S_ + i]);
        y2 += bf2f(partY[base + (long)(64 + d) * S_ + i]);
        z  += partZ[((long)(jc * 2 + b) * 4 + h) * S_ + i];
    }
    outav[((long)b * 256 + h * 64 + d) * S_ + i] = f2bf(y1 / z + y2);
}

// ---------------- residual add (remap) + LN2 over C=4 + GDFN pin (hbuf bf16) ----------------
__global__ __launch_bounds__(256) void resid_pin_kernel(
    const float* __restrict__ buffer, const float* __restrict__ proj,
    const float* __restrict__ g2, const float* __restrict__ b2,
    const float* __restrict__ w_pin,
    float* __restrict__ x2, short* __restrict__ hbuf)
{
    int s = blockIdx.x * 256 + threadIdx.x;
    int bn = blockIdx.y;
    int b = bn / N_, n = bn % N_;
    float v[4];
    float sum = 0.f;
    #pragma unroll
    for (int c = 0; c < 4; ++c) {
        float xr = buffer[((long)(b * 4 + c) * N_ + n) * S_ + s];
        float pr = proj[((long)b * TOK_ + c * N_ + n) * S_ + s];
        v[c] = xr + pr;
        x2[((long)bn * 4 + c) * S_ + s] = v[c];
        sum += v[c];
    }
    float mean = sum * 0.25f;
    float var = 0.f;
    #pragma unroll
    for (int c = 0; c < 4; ++c) { float dd = v[c] - mean; var += dd * dd; }
    var *= 0.25f;
    float inv = rsqrtf(var + 1e-6f);
    float e[4];
    #pragma unroll
    for (int c = 0; c < 4; ++c) e[c] = (v[c] - mean) * inv * g2[c] + b2[c];
    for (int o = 0; o < 2 * HF_; ++o) {
        float a = 0.f;
        #pragma unroll
        for (int c = 0; c < 4; ++c) a += w_pin[o * 4 + c] * e[c];
        hbuf[((long)bn * (2 * HF_) + o) * S_ + s] = f2bf(a);
    }
}

// ------- fused GDFN tail: dwconv3(hbuf bf16) + gelu-gate + pout + residual + remap -------
__global__ __launch_bounds__(448) void gdfn_kernel(
    const short* __restrict__ hbuf, const float* __restrict__ w_dw,
    const float* __restrict__ w_pout, const float* __restrict__ x2,
    float* __restrict__ out)
{
    int xt = blockIdx.x;             // 0..3 (64-wide x tiles)
    int bn = blockIdx.y;             // 0..447
    int b = bn / N_, n = bn % N_;
    int x0 = xt * 64;
    __shared__ float tile[20][7][66];
    int tid = threadIdx.x;
    for (int idx = tid; idx < 20 * 7 * 66; idx += 448) {
        int ch = idx / (7 * 66); int rem = idx % (7 * 66);
        int y = rem / 66; int xx = rem % 66;
        int gx = x0 + xx - 1;
        float v = 0.f;
        if (gx >= 0 && gx < W_) v = bf2f(hbuf[((long)bn * 20 + ch) * S_ + y * W_ + gx]);
        tile[ch][y][xx] = v;
    }
    __syncthreads();
    int y = tid / 64, x = tid & 63;
    float hd[20];
    #pragma unroll
    for (int ch = 0; ch < 20; ++ch) {
        const float* wp = w_dw + ch * 9;
        float acc = 0.f;
        #pragma unroll
        for (int dy = -1; dy <= 1; ++dy) {
            int yy = y + dy;
            if (yy < 0 || yy >= V_) continue;
            #pragma unroll
            for (int dx = -1; dx <= 1; ++dx)
                acc += tile[ch][yy][x + 1 + dx] * wp[(dy + 1) * 3 + (dx + 1)];
        }
        hd[ch] = acc;
    }
    float g[HF_];
    #pragma unroll
    for (int f = 0; f < HF_; ++f) {
        float h1 = hd[f];
        g[f] = 0.5f * h1 * (1.f + erff(h1 * 0.70710678118654752f)) * hd[HF_ + f];
    }
    int s = y * W_ + x0 + x;
    #pragma unroll
    for (int c = 0; c < 4; ++c) {
        float a = 0.f;
        #pragma unroll
        for (int f = 0; f < HF_; ++f) a += w_pout[c * HF_ + f] * g[f];
        out[((long)(b * 4 + c) * N_ + n) * S_ + s] = x2[((long)bn * 4 + c) * S_ + s] + a;
    }
}

extern "C" void kernel_launch(void* const* d_in, const int* in_sizes, int n_in,
                              void* d_out, int out_size, void* d_ws, size_t ws_size,
                              hipStream_t stream)
{
    const float* buffer = (const float*)d_in[0];
    const float* w_in   = (const float*)d_in[1];
    const float* temp   = (const float*)d_in[2];
    const float* ln1_g  = (const float*)d_in[3];
    const float* ln1_b  = (const float*)d_in[4];
    const float* w_qkv  = (const float*)d_in[5];
    const float* w_qkv_dw = (const float*)d_in[6];
    const float* w_proj = (const float*)d_in[7];
    const float* w_attca = (const float*)d_in[8];
    const float* ln2_g  = (const float*)d_in[9];
    const float* ln2_b  = (const float*)d_in[10];
    const float* w_pin  = (const float*)d_in[11];
    const float* w_dw   = (const float*)d_in[12];
    const float* w_pout = (const float*)d_in[13];
    float* out = (float*)d_out;

    float* ws = (float*)d_ws;
    float* qkvd    = ws;                        // 2,752,512
    short* qn      = (short*)(ws + 2752512);    // 458,752 f
    short* kn      = (short*)(ws + 3211264);    // 458,752 f
    short* vbf     = (short*)(ws + 3670016);    // 458,752 f
    short* partY   = (short*)(ws + 4128768);    // 7,340,032 f (bf16, JC=8)
    float* partZ   = ws + 11468800;             // 114,688
    short* outav   = (short*)(ws + 11583488);   // 458,752 f (bf16)
    float* xw      = ws + 12042240;             // 917,504
    float* colsum  = ws + 12959744;             // 28,672
    float* qkv     = ws + 12988416;             // 2,752,512
    float* outproj = ws + 15740928;             // 3,211,264
    float* x2      = ws + 18952192;             // 3,211,264
    short* hbuf    = (short*)(ws + 22163456);   // 8,028,160 f (bf16)
    // end: 30,191,616 floats = 120.8 MB

    // 1. linear_in + LN1 column-stat partials
    gemm_kernel<true, false, false><<<dim3(14, 4, 2), 256, 0, stream>>>(
        w_in, buffer, xw, EMB_, S_, TOK_, (long)TOK_ * S_, (long)EMB_ * S_,
        nullptr, colsum, nullptr, nullptr);

    // 2. qkv 1x1 conv with LN1 fused on B
    gemm_kernel<false, true, false><<<dim3(14, 12, 2), 256, 0, stream>>>(
        w_qkv, xw, qkv, 3 * EMB_, S_, EMB_, (long)EMB_ * S_, (long)3 * EMB_ * S_,
        colsum, nullptr, ln1_g, ln1_b);

    // 3. depthwise 3x3 on qkv (+ bf16 V emit)
    {
        long total = (long)B_ * 3 * EMB_ * S_;
        dwconv3_kernel<<<(int)((total + 255) / 256), 256, 0, stream>>>(
            qkv, w_qkv_dw, qkvd, vbf, total, 3 * EMB_);
    }

    // 4. q,k -> normalized bf16 (temp folded into q)
    headnorm_kernel<<<dim3(28, 8, 2), 256, 0, stream>>>(qkvd, temp, qn, kn);

    // 5. fused attention partials (JC=8, bf16 dbuf exchange, pipelined K/V)
    attn_kernel<<<dim3(112, JC_, B_), 256, 0, stream>>>(qn, kn, vbf, w_attca, partY, partZ);

    // 6. combine partials -> outav (bf16)
    combine_kernel<<<3584, 256, 0, stream>>>(partY, partZ, outav);

    // 7. proj (B is bf16)
    gemm_kernel<false, false, true><<<dim3(14, 14, 2), 256, 0, stream>>>(
        w_proj, outav, outproj, TOK_, S_, EMB_, (long)EMB_ * S_, (long)TOK_ * S_,
        nullptr, nullptr, nullptr, nullptr);

    // 8. residual + LN2 + GDFN pin (bf16 hbuf)
    resid_pin_kernel<<<dim3(7, B_ * N_), 256, 0, stream>>>(
        buffer, outproj, ln2_g, ln2_b, w_pin, x2, hbuf);

    // 9. fused GDFN tail
    gdfn_kernel<<<dim3(4, B_ * N_), 448, 0, stream>>>(hbuf, w_dw, w_pout, x2, out);
}

// Round 15
// 194.939 us; speedup vs baseline: 1.0358x; 1.0358x over previous
//
#include <hip/hip_runtime.h>
#include <math.h>

#define B_ 2
#define C_ 4
#define N_ 224
#define V_ 7
#define W_ 256
#define S_ 1792
#define EMB_ 256
#define H_ 4
#define D_ 64
#define TOK_ 896
#define HF_ 10
#define JC_ 8
#define JRANGE_ (S_ / JC_)      /* 224 */
#define JSTEPS_ (JRANGE_ / 32)  /* 7 */

typedef __attribute__((ext_vector_type(8))) short short8;
typedef __attribute__((ext_vector_type(4))) float f32x4;

#define MFMA16(a, b, c) __builtin_amdgcn_mfma_f32_16x16x32_bf16(a, b, c, 0, 0, 0)

__device__ inline short f2bf(float f) {
    union { float f; unsigned u; } x; x.f = f;
    unsigned u = x.u;
    unsigned r = (u + 0x7fffu + ((u >> 16) & 1u)) >> 16;
    return (short)r;
}
__device__ inline float bf2f(short s) {
    union { unsigned u; float f; } x;
    x.u = ((unsigned)(unsigned short)s) << 16;
    return x.f;
}
// pack two f32 -> one dword of 2 bf16 (RNE), single instruction on gfx950
__device__ inline unsigned cvtpk_bf16(float lo, float hi) {
    unsigned r;
    asm("v_cvt_pk_bf16_f32 %0, %1, %2" : "=v"(r) : "v"(lo), "v"(hi));
    return r;
}

// ---- 64M x 128N x 32K bf16 MFMA GEMM, XOR-swizzled LDS ----
template<bool COLSUM, bool LNB, bool BBF>
__global__ __launch_bounds__(256) void gemm_kernel(
    const float* __restrict__ A, const void* __restrict__ Bv, float* __restrict__ Cm,
    int M, int N, int K, long b_bs, long c_bs,
    const float* __restrict__ csin, float* __restrict__ csout,
    const float* __restrict__ lg, const float* __restrict__ lb)
{
    const int bz = blockIdx.z;
    Cm += (long)bz * c_bs;
    const int m0 = blockIdx.y * 64, n0 = blockIdx.x * 128;
    __shared__ __align__(16) short As[64 * 32];
    __shared__ __align__(16) short Bs[128 * 32];
    const int t = threadIdx.x;
    const int lane = t & 63, wave = t >> 6;
    const int wr = wave >> 1, wc = wave & 1;
    const int col = lane & 15, grp = lane >> 4;
    const int arow = t >> 2, akc = (t & 3) * 8;
    const int bn = t & 127, bkc = (t >> 7) * 16;
    float mean = 0.f, rstd = 1.f;
    if (LNB) {
        float s = 0.f, q = 0.f;
        #pragma unroll
        for (int mb = 0; mb < 4; ++mb) {
            s += csin[((long)(bz * 4 + mb) * 2 + 0) * N + n0 + bn];
            q += csin[((long)(bz * 4 + mb) * 2 + 1) * N + n0 + bn];
        }
        mean = s * (1.f / 256.f);
        rstd = rsqrtf(q * (1.f / 256.f) - mean * mean + 1e-6f);
    }
    f32x4 acc[2][4];
    #pragma unroll
    for (int i = 0; i < 2; ++i)
        #pragma unroll
        for (int j = 0; j < 4; ++j) acc[i][j] = (f32x4){0.f, 0.f, 0.f, 0.f};
    for (int k0 = 0; k0 < K; k0 += 32) {
        {
            const float* ap = &A[(long)(m0 + arow) * K + k0 + akc];
            f32x4 a0 = *(const f32x4*)ap;
            f32x4 a1 = *(const f32x4*)(ap + 4);
            short8 av;
            av[0] = f2bf(a0[0]); av[1] = f2bf(a0[1]); av[2] = f2bf(a0[2]); av[3] = f2bf(a0[3]);
            av[4] = f2bf(a1[0]); av[5] = f2bf(a1[1]); av[6] = f2bf(a1[2]); av[7] = f2bf(a1[3]);
            int abyte = (arow << 6) + (akc << 1);
            *(short8*)((char*)As + (abyte ^ ((arow & 7) << 4))) = av;
        }
        {
            short8 b0, b1;
            if (BBF) {
                const short* Bp = (const short*)Bv + (long)bz * b_bs;
                #pragma unroll
                for (int j = 0; j < 8; ++j) {
                    b0[j] = Bp[(long)(k0 + bkc + j) * N + n0 + bn];
                    b1[j] = Bp[(long)(k0 + bkc + 8 + j) * N + n0 + bn];
                }
            } else {
                const float* Bp = (const float*)Bv + (long)bz * b_bs;
                #pragma unroll
                for (int j = 0; j < 16; ++j) {
                    float v = Bp[(long)(k0 + bkc + j) * N + n0 + bn];
                    if (LNB) v = fmaf((v - mean) * rstd, lg[k0 + bkc + j], lb[k0 + bkc + j]);
                    if (j < 8) b0[j] = f2bf(v); else b1[j - 8] = f2bf(v);
                }
            }
            int bbyte = (bn << 6) + (bkc << 1);
            *(short8*)((char*)Bs + ((bbyte) ^ ((bn & 7) << 4))) = b0;
            *(short8*)((char*)Bs + ((bbyte + 16) ^ ((bn & 7) << 4))) = b1;
        }
        __syncthreads();
        short8 af[2], bfv[4];
        #pragma unroll
        for (int mm = 0; mm < 2; ++mm) {
            int r = wr * 32 + mm * 16 + col;
            af[mm] = *(const short8*)((const char*)As + (((r << 6) + (grp << 4)) ^ ((r & 7) << 4)));
        }
        #pragma unroll
        for (int nn = 0; nn < 4; ++nn) {
            int r = wc * 64 + nn * 16 + col;
            bfv[nn] = *(const short8*)((const char*)Bs + (((r << 6) + (grp << 4)) ^ ((r & 7) << 4)));
        }
        #pragma unroll
        for (int mm = 0; mm < 2; ++mm)
            #pragma unroll
            for (int nn = 0; nn < 4; ++nn)
                acc[mm][nn] = MFMA16(af[mm], bfv[nn], acc[mm][nn]);
        __syncthreads();
    }
    #pragma unroll
    for (int mm = 0; mm < 2; ++mm)
        #pragma unroll
        for (int nn = 0; nn < 4; ++nn)
            #pragma unroll
            for (int r = 0; r < 4; ++r)
                Cm[(long)(m0 + wr * 32 + mm * 16 + grp * 4 + r) * N
                   + n0 + wc * 64 + nn * 16 + col] = acc[mm][nn][r];
    if (COLSUM) {
        float* red = (float*)As;
        #pragma unroll
        for (int nn = 0; nn < 4; ++nn) {
            float s = 0.f, q = 0.f;
            #pragma unroll
            for (int mm = 0; mm < 2; ++mm)
                #pragma unroll
                for (int r = 0; r < 4; ++r) { float v = acc[mm][nn][r]; s += v; q += v * v; }
            s += __shfl_xor(s, 16, 64); s += __shfl_xor(s, 32, 64);
            q += __shfl_xor(q, 16, 64); q += __shfl_xor(q, 32, 64);
            if (lane < 16) {
                int cidx = wc * 64 + nn * 16 + col;
                red[(wr * 128 + cidx) * 2]     = s;
                red[(wr * 128 + cidx) * 2 + 1] = q;
            }
        }
        __syncthreads();
        if (wave < 2 && lane < 16) {
            #pragma unroll
            for (int nn = 0; nn < 4; ++nn) {
                int cidx = wc * 64 + nn * 16 + col;
                float s = red[cidx * 2]     + red[(128 + cidx) * 2];
                float q = red[cidx * 2 + 1] + red[(128 + cidx) * 2 + 1];
                csout[((long)(bz * 4 + blockIdx.y) * 2 + 0) * N + n0 + cidx] = s;
                csout[((long)(bz * 4 + blockIdx.y) * 2 + 1) * N + n0 + cidx] = q;
            }
        }
    }
}

// --- depthwise 3x3, SAME; q/k channels -> fp32 qkvd; v channels (512..767) -> bf16 vbf only ---
__global__ void dwconv3_kernel(const float* __restrict__ X, const float* __restrict__ Wt,
                               float* __restrict__ Y, short* __restrict__ vbf,
                               long total, int Ch)
{
    long idx = (long)blockIdx.x * blockDim.x + threadIdx.x;
    long stride = (long)gridDim.x * blockDim.x;
    for (; idx < total; idx += stride) {
        int w = (int)(idx % W_);
        long t = idx / W_;
        int h = (int)(t % V_); t /= V_;
        int ch = (int)(t % Ch);
        long img_ch = idx / ((long)V_ * W_);
        const float* wp = Wt + ch * 9;
        const float* xp = X + img_ch * (V_ * W_);
        float acc = 0.f;
        #pragma unroll
        for (int dy = -1; dy <= 1; ++dy) {
            int h2 = h + dy;
            if (h2 < 0 || h2 >= V_) continue;
            #pragma unroll
            for (int dx = -1; dx <= 1; ++dx) {
                int w2 = w + dx;
                if (w2 < 0 || w2 >= W_) continue;
                acc += xp[h2 * W_ + w2] * wp[(dy + 1) * 3 + (dx + 1)];
            }
        }
        if (ch < 512) {
            Y[idx] = acc;
        } else {
            int b = (int)(t / Ch);
            vbf[((long)b * 256 + (ch - 512)) * S_ + h * W_ + w] = f2bf(acc);
        }
    }
}

// ------- head transpose + L2-normalize -> bf16 [B][H][S][64]; q also scaled by temp -------
__global__ __launch_bounds__(256) void headnorm_kernel(
    const float* __restrict__ qkvd, const float* __restrict__ temp,
    short* __restrict__ qn, short* __restrict__ kn)
{
    int s0 = blockIdx.x * 64;
    int bh = blockIdx.y; int b = bh >> 2, h = bh & 3;
    int isq = blockIdx.z;                    // 0 = k, 1 = q
    int ch0 = b * 768 + (isq ? 0 : EMB_) + h * 64;
    short* dst = (isq ? qn : kn) + (long)bh * S_ * 64;
    __shared__ float tile[64][65];
    __shared__ float red[64][4];
    int t = threadIdx.x;
    int sl = t & 63, dg = t >> 6;
    float part = 0.f;
    for (int dd = 0; dd < 16; ++dd) {
        int d = dg * 16 + dd;
        float v = qkvd[(long)(ch0 + d) * S_ + s0 + sl];
        tile[sl][d] = v;
        part += v * v;
    }
    red[sl][dg] = part;
    __syncthreads();
    int d = t & 63, sg = t >> 6;
    float tmul = isq ? temp[h] : 1.f;
    for (int si = 0; si < 16; ++si) {
        int s = sg * 16 + si;
        float nrm = sqrtf(red[s][0] + red[s][1] + red[s][2] + red[s][3]);
        float scale = tmul / fmaxf(nrm, 1e-12f);
        dst[(long)(s0 + s) * 64 + d] = f2bf(tile[s][d] * scale);
    }
}

// --- fused attention, swapped-QK; i-tile 32 (2 M-tiles/wave, K/V reused); dbuf exch ---
__global__ __launch_bounds__(256) void attn_kernel(
    const short* __restrict__ qn, const short* __restrict__ kn,
    const short* __restrict__ vbf, const float* __restrict__ wat,
    short* __restrict__ partY, float* __restrict__ partZ)
{
    const int h = threadIdx.x >> 6;           // wave = head
    const int lane = threadIdx.x & 63;
    const int col = lane & 15, grp = lane >> 4;
    const int itile = blockIdx.x;             // 0..55
    const int jc = blockIdx.y;                // 0..JC_-1
    const int b = blockIdx.z;
    const int ibase = itile * 32;
    const int bh = b * 4 + h;

    const short* qrow0 = qn + ((long)bh * S_ + ibase + col) * 64 + grp * 8;
    const short* qrow1 = qrow0 + 16 * 64;
    short8 qa0 = *(const short8*)qrow0;
    short8 qa1 = *(const short8*)(qrow0 + 32);
    short8 qb0 = *(const short8*)qrow1;
    short8 qb1 = *(const short8*)(qrow1 + 32);
    float wsc[4], wsh[4];
    #pragma unroll
    for (int hh = 0; hh < 4; ++hh) { wsc[hh] = wat[h * 4 + hh]; wsh[hh] = wat[(4 + h) * 4 + hh]; }

    __shared__ float exch[2][4][32][34];      // [buf][head][jloc][i 0..31, stride 34]

    f32x4 y1[2][4], y2[2][4];
    #pragma unroll
    for (int it = 0; it < 2; ++it)
        #pragma unroll
        for (int dt = 0; dt < 4; ++dt) {
            y1[it][dt] = (f32x4){0.f, 0.f, 0.f, 0.f};
            y2[it][dt] = (f32x4){0.f, 0.f, 0.f, 0.f};
        }
    float z0 = 0.f, z1 = 0.f;
    const short* kbase = kn + (long)bh * S_ * 64;
    const short* vbase = vbf + ((long)b * 256 + h * 64) * S_;
    const int joffA = (col & 3) + 8 * (col >> 2);   // permuted j for A(M)-rows
    const int jbase0 = jc * JRANGE_;

    // prefetch step 0 K/V rows
    short8 kc0, kc1, kc2, kc3, vc0, vc1, vc2, vc3;
    {
        const short* kr0 = kbase + (long)(jbase0 + joffA) * 64 + grp * 8;
        const short* kr1 = kbase + (long)(jbase0 + joffA + 4) * 64 + grp * 8;
        kc0 = *(const short8*)kr0; kc1 = *(const short8*)(kr0 + 32);
        kc2 = *(const short8*)kr1; kc3 = *(const short8*)(kr1 + 32);
        const short* vr = vbase + (long)col * S_ + jbase0 + grp * 8;
        vc0 = *(const short8*)vr;
        vc1 = *(const short8*)(vr + 16 * S_);
        vc2 = *(const short8*)(vr + 32 * S_);
        vc3 = *(const short8*)(vr + 48 * S_);
    }

    for (int jt = 0; jt < JSTEPS_; ++jt) {
        const int jbase = jbase0 + jt * 32;
        const int buf = jt & 1;
        // prefetch next step
        short8 kp0, kp1, kp2, kp3, vp0, vp1, vp2, vp3;
        if (jt + 1 < JSTEPS_) {
            const int jb2 = jbase + 32;
            const short* kr0 = kbase + (long)(jb2 + joffA) * 64 + grp * 8;
            const short* kr1 = kbase + (long)(jb2 + joffA + 4) * 64 + grp * 8;
            kp0 = *(const short8*)kr0; kp1 = *(const short8*)(kr0 + 32);
            kp2 = *(const short8*)kr1; kp3 = *(const short8*)(kr1 + 32);
            const short* vr = vbase + (long)col * S_ + jb2 + grp * 8;
            vp0 = *(const short8*)vr;
            vp1 = *(const short8*)(vr + 16 * S_);
            vp2 = *(const short8*)(vr + 32 * S_);
            vp3 = *(const short8*)(vr + 48 * S_);
        } else {
            kp0 = kc0; kp1 = kc1; kp2 = kc2; kp3 = kc3;
            vp0 = vc0; vp1 = vc1; vp2 = vc2; vp3 = vc3;
        }
        // QK^T for both i-tiles (K rows shared)
        f32x4 lfA[2], lfB[2];
        {
            f32x4 a = (f32x4){0.f, 0.f, 0.f, 0.f};
            a = MFMA16(kc0, qa0, a); a = MFMA16(kc1, qa1, a); lfA[0] = a;
        }
        {
            f32x4 a = (f32x4){0.f, 0.f, 0.f, 0.f};
            a = MFMA16(kc2, qa0, a); a = MFMA16(kc3, qa1, a); lfA[1] = a;
        }
        {
            f32x4 a = (f32x4){0.f, 0.f, 0.f, 0.f};
            a = MFMA16(kc0, qb0, a); a = MFMA16(kc1, qb1, a); lfB[0] = a;
        }
        {
            f32x4 a = (f32x4){0.f, 0.f, 0.f, 0.f};
            a = MFMA16(kc2, qb0, a); a = MFMA16(kc3, qb1, a); lfB[1] = a;
        }
        float a1A[2][4], eeA[2][4], a1B[2][4], eeB[2][4];
        #pragma unroll
        for (int tt = 0; tt < 2; ++tt)
            #pragma unroll
            for (int r = 0; r < 4; ++r) {
                {
                    float l = lfA[tt][r];
                    float rr = fmaxf(l, 0.f);
                    float s1 = rr * rr;
                    float u = fmaf(s1 * s1, 0.0713548162726f * s1, 1.59576912161f * s1);
                    float sg = __builtin_amdgcn_rcpf(1.f + __expf(-u));
                    float a1 = s1 * sg * s1;
                    a1A[tt][r] = a1;
                    eeA[tt][r] = __expf(l);
                    exch[buf][h][r + 4 * tt + 8 * grp][col] = a1;
                }
                {
                    float l = lfB[tt][r];
                    float rr = fmaxf(l, 0.f);
                    float s1 = rr * rr;
                    float u = fmaf(s1 * s1, 0.0713548162726f * s1, 1.59576912161f * s1);
                    float sg = __builtin_amdgcn_rcpf(1.f + __expf(-u));
                    float a1 = s1 * sg * s1;
                    a1B[tt][r] = a1;
                    eeB[tt][r] = __expf(l);
                    exch[buf][h][r + 4 * tt + 8 * grp][col + 16] = a1;
                }
            }
        __syncthreads();
        // i-tile 0: mix + AV
        {
            union { short8 s; unsigned u[4]; } pa_, pb_;
            #pragma unroll
            for (int tt = 0; tt < 2; ++tt) {
                float scv[4], shv[4];
                #pragma unroll
                for (int r = 0; r < 4; ++r) {
                    int jloc = r + 4 * tt + 8 * grp;
                    float sc = 0.f, sh = 0.f;
                    #pragma unroll
                    for (int hh = 0; hh < 4; ++hh) {
                        float a1v = (hh == h) ? a1A[tt][r] : exch[buf][hh][jloc][col];
                        sc += a1v * wsc[hh];
                        sh += a1v * wsh[hh];
                    }
                    float e = eeA[tt][r];
                    z0 += e;
                    scv[r] = e * (1.f + sc);
                    shv[r] = sh;
                }
                pa_.u[tt * 2]     = cvtpk_bf16(scv[0], scv[1]);
                pa_.u[tt * 2 + 1] = cvtpk_bf16(scv[2], scv[3]);
                pb_.u[tt * 2]     = cvtpk_bf16(shv[0], shv[1]);
                pb_.u[tt * 2 + 1] = cvtpk_bf16(shv[2], shv[3]);
            }
            y1[0][0] = MFMA16(pa_.s, vc0, y1[0][0]); y2[0][0] = MFMA16(pb_.s, vc0, y2[0][0]);
            y1[0][1] = MFMA16(pa_.s, vc1, y1[0][1]); y2[0][1] = MFMA16(pb_.s, vc1, y2[0][1]);
            y1[0][2] = MFMA16(pa_.s, vc2, y1[0][2]); y2[0][2] = MFMA16(pb_.s, vc2, y2[0][2]);
            y1[0][3] = MFMA16(pa_.s, vc3, y1[0][3]); y2[0][3] = MFMA16(pb_.s, vc3, y2[0][3]);
        }
        // i-tile 1: mix + AV (reuses the same V registers)
        {
            union { short8 s; unsigned u[4]; } pa_, pb_;
            #pragma unroll
            for (int tt = 0; tt < 2; ++tt) {
                float scv[4], shv[4];
                #pragma unroll
                for (int r = 0; r < 4; ++r) {
                    int jloc = r + 4 * tt + 8 * grp;
                    float sc = 0.f, sh = 0.f;
                    #pragma unroll
                    for (int hh = 0; hh < 4; ++hh) {
                        float a1v = (hh == h) ? a1B[tt][r] : exch[buf][hh][jloc][col + 16];
                        sc += a1v * wsc[hh];
                        sh += a1v * wsh[hh];
                    }
                    float e = eeB[tt][r];
                    z1 += e;
                    scv[r] = e * (1.f + sc);
                    shv[r] = sh;
                }
                pa_.u[tt * 2]     = cvtpk_bf16(scv[0], scv[1]);
                pa_.u[tt * 2 + 1] = cvtpk_bf16(scv[2], scv[3]);
                pb_.u[tt * 2]     = cvtpk_bf16(shv[0], shv[1]);
                pb_.u[tt * 2 + 1] = cvtpk_bf16(shv[2], shv[3]);
            }
            y1[1][0] = MFMA16(pa_.s, vc0, y1[1][0]); y2[1][0] = MFMA16(pb_.s, vc0, y2[1][0]);
            y1[1][1] = MFMA16(pa_.s, vc1, y1[1][1]); y2[1][1] = MFMA16(pb_.s, vc1, y2[1][1]);
            y1[1][2] = MFMA16(pa_.s, vc2, y1[1][2]); y2[1][2] = MFMA16(pb_.s, vc2, y2[1][2]);
            y1[1][3] = MFMA16(pa_.s, vc3, y1[1][3]); y2[1][3] = MFMA16(pb_.s, vc3, y2[1][3]);
        }
        // rotate pipeline registers
        kc0 = kp0; kc1 = kp1; kc2 = kp2; kc3 = kp3;
        vc0 = vp0; vc1 = vp1; vc2 = vp2; vc3 = vp3;
    }

    // Z: reduce over grp replicas
    z0 += __shfl_xor(z0, 16, 64);
    z0 += __shfl_xor(z0, 32, 64);
    z1 += __shfl_xor(z1, 16, 64);
    z1 += __shfl_xor(z1, 32, 64);
    if (grp == 0) {
        partZ[((long)(jc * 2 + b) * 4 + h) * S_ + ibase + col] = z0;
        partZ[((long)(jc * 2 + b) * 4 + h) * S_ + ibase + 16 + col] = z1;
    }

    // epilogue: transpose Y frags via wave-private LDS, write bf16 [d][i] coalesced over i
    __syncthreads();
    float* tb = &exch[0][h][0][0];
    long ybase = ((((long)jc * 2 + b) * 4 + h) * 2) * 64 * S_;
    #pragma unroll
    for (int it = 0; it < 2; ++it) {
        for (int acc = 0; acc < 2; ++acc) {
            #pragma unroll
            for (int dt = 0; dt < 4; ++dt) {
                f32x4 y = acc ? y2[it][dt] : y1[it][dt];
                #pragma unroll
                for (int r = 0; r < 4; ++r) tb[(grp * 4 + r) * 17 + col] = y[r];
                #pragma unroll
                for (int p = 0; p < 4; ++p) {
                    float val = tb[col * 17 + p * 4 + grp];
                    partY[ybase + ((long)acc * 64 + dt * 16 + p * 4 + grp) * S_
                          + ibase + it * 16 + col] = f2bf(val);
                }
            }
        }
    }
}

// ---------------- combine j-chunks: outav = (sum Y1)/(sum Z) + sum Y2, bf16 ----------------
__global__ __launch_bounds__(256) void combine_kernel(
    const short* __restrict__ partY, const float* __restrict__ partZ,
    short* __restrict__ outav)
{
    int idx = blockIdx.x * 256 + threadIdx.x;
    int i = idx % S_;
    int t = idx / S_;
    int d = t & 63; t >>= 6;
    int h = t & 3; int b = t >> 2;
    float y1 = 0.f, y2 = 0.f, z = 0.f;
    #pragma unroll
    for (int jc = 0; jc < JC_; ++jc) {
        long base = ((((long)jc * 2 + b) * 4 + h) * 2) * 64 * S_;
        y1 += bf2f(partY[base + (long)d * S_ + i]);
        y2 += bf2f(partY[base + (long)(64 + d) * S_ + i]);
        z  += partZ[((long)(jc * 2 + b) * 4 + h) * S_ + i];
    }
    outav[((long)b * 256 + h * 64 + d) * S_ + i] = f2bf(y1 / z + y2);
}

// ------- residual add (remap) + LN2 over C=4 + GDFN pin (x2 bf16, hbuf bf16) -------
__global__ __launch_bounds__(256) void resid_pin_kernel(
    const float* __restrict__ buffer, const float* __restrict__ proj,
    const float* __restrict__ g2, const float* __restrict__ b2,
    const float* __restrict__ w_pin,
    short* __restrict__ x2, short* __restrict__ hbuf)
{
    int s = blockIdx.x * 256 + threadIdx.x;
    int bn = blockIdx.y;
    int b = bn / N_, n = bn % N_;
    float v[4];
    float sum = 0.f;
    #pragma unroll
    for (int c = 0; c < 4; ++c) {
        float xr = buffer[((long)(b * 4 + c) * N_ + n) * S_ + s];
        float pr = proj[((long)b * TOK_ + c * N_ + n) * S_ + s];
        v[c] = xr + pr;
        x2[((long)bn * 4 + c) * S_ + s] = f2bf(v[c]);
        sum += v[c];
    }
    float mean = sum * 0.25f;
    float var = 0.f;
    #pragma unroll
    for (int c = 0; c < 4; ++c) { float dd = v[c] - mean; var += dd * dd; }
    var *= 0.25f;
    float inv = rsqrtf(var + 1e-6f);
    float e[4];
    #pragma unroll
    for (int c = 0; c < 4; ++c) e[c] = (v[c] - mean) * inv * g2[c] + b2[c];
    for (int o = 0; o < 2 * HF_; ++o) {
        float a = 0.f;
        #pragma unroll
        for (int c = 0; c < 4; ++c) a += w_pin[o * 4 + c] * e[c];
        hbuf[((long)bn * (2 * HF_) + o) * S_ + s] = f2bf(a);
    }
}

// ------- fused GDFN tail: dwconv3(hbuf bf16) + gelu-gate + pout + residual + remap -------
__global__ __launch_bounds__(448) void gdfn_kernel(
    const short* __restrict__ hbuf, const float* __restrict__ w_dw,
    const float* __restrict__ w_pout, const short* __restrict__ x2,
    float* __restrict__ out)
{
    int xt = blockIdx.x;             // 0..3 (64-wide x tiles)
    int bn = blockIdx.y;             // 0..447
    int b = bn / N_, n = bn % N_;
    int x0 = xt * 64;
    __shared__ float tile[20][7][66];
    int tid = threadIdx.x;
    for (int idx = tid; idx < 20 * 7 * 66; idx += 448) {
        int ch = idx / (7 * 66); int rem = idx % (7 * 66);
        int y = rem / 66; int xx = rem % 66;
        int gx = x0 + xx - 1;
        float v = 0.f;
        if (gx >= 0 && gx < W_) v = bf2f(hbuf[((long)bn * 20 + ch) * S_ + y * W_ + gx]);
        tile[ch][y][xx] = v;
    }
    __syncthreads();
    int y = tid / 64, x = tid & 63;
    float hd[20];
    #pragma unroll
    for (int ch = 0; ch < 20; ++ch) {
        const float* wp = w_dw + ch * 9;
        float acc = 0.f;
        #pragma unroll
        for (int dy = -1; dy <= 1; ++dy) {
            int yy = y + dy;
            if (yy < 0 || yy >= V_) continue;
            #pragma unroll
            for (int dx = -1; dx <= 1; ++dx)
                acc += tile[ch][yy][x + 1 + dx] * wp[(dy + 1) * 3 + (dx + 1)];
        }
        hd[ch] = acc;
    }
    float g[HF_];
    #pragma unroll
    for (int f = 0; f < HF_; ++f) {
        float h1 = hd[f];
        g[f] = 0.5f * h1 * (1.f + erff(h1 * 0.70710678118654752f)) * hd[HF_ + f];
    }
    int s = y * W_ + x0 + x;
    #pragma unroll
    for (int c = 0; c < 4; ++c) {
        float a = 0.f;
        #pragma unroll
        for (int f = 0; f < HF_; ++f) a += w_pout[c * HF_ + f] * g[f];
        out[((long)(b * 4 + c) * N_ + n) * S_ + s] =
            bf2f(x2[((long)bn * 4 + c) * S_ + s]) + a;
    }
}

extern "C" void kernel_launch(void* const* d_in, const int* in_sizes, int n_in,
                              void* d_out, int out_size, void* d_ws, size_t ws_size,
                              hipStream_t stream)
{
    const float* buffer = (const float*)d_in[0];
    const float* w_in   = (const float*)d_in[1];
    const float* temp   = (const float*)d_in[2];
    const float* ln1_g  = (const float*)d_in[3];
    const float* ln1_b  = (const float*)d_in[4];
    const float* w_qkv  = (const float*)d_in[5];
    const float* w_qkv_dw = (const float*)d_in[6];
    const float* w_proj = (const float*)d_in[7];
    const float* w_attca = (const float*)d_in[8];
    const float* ln2_g  = (const float*)d_in[9];
    const float* ln2_b  = (const float*)d_in[10];
    const float* w_pin  = (const float*)d_in[11];
    const float* w_dw   = (const float*)d_in[12];
    const float* w_pout = (const float*)d_in[13];
    float* out = (float*)d_out;

    float* ws = (float*)d_ws;
    float* qkvd    = ws;                        // 2,752,512 (q/k channels used)
    short* qn      = (short*)(ws + 2752512);    // 458,752 f
    short* kn      = (short*)(ws + 3211264);    // 458,752 f
    short* vbf     = (short*)(ws + 3670016);    // 458,752 f
    short* partY   = (short*)(ws + 4128768);    // 7,340,032 f (bf16, JC=8)
    float* partZ   = ws + 11468800;             // 114,688
    short* outav   = (short*)(ws + 11583488);   // 458,752 f (bf16)
    float* xw      = ws + 12042240;             // 917,504
    float* colsum  = ws + 12959744;             // 28,672
    float* qkv     = ws + 12988416;             // 2,752,512
    float* outproj = ws + 15740928;             // 3,211,264
    short* x2      = (short*)(ws + 18952192);   // 1,605,632 f (bf16)
    short* hbuf    = (short*)(ws + 20557824);   // 8,028,160 f (bf16)
    // end: 28,585,984 floats = 114.3 MB

    // 1. linear_in + LN1 column-stat partials
    gemm_kernel<true, false, false><<<dim3(14, 4, 2), 256, 0, stream>>>(
        w_in, buffer, xw, EMB_, S_, TOK_, (long)TOK_ * S_, (long)EMB_ * S_,
        nullptr, colsum, nullptr, nullptr);

    // 2. qkv 1x1 conv with LN1 fused on B
    gemm_kernel<false, true, false><<<dim3(14, 12, 2), 256, 0, stream>>>(
        w_qkv, xw, qkv, 3 * EMB_, S_, EMB_, (long)EMB_ * S_, (long)3 * EMB_ * S_,
        colsum, nullptr, ln1_g, ln1_b);

    // 3. depthwise 3x3 on qkv (q/k -> fp32 qkvd; v -> bf16 vbf only)
    {
        long total = (long)B_ * 3 * EMB_ * S_;
        dwconv3_kernel<<<(int)((total + 255) / 256), 256, 0, stream>>>(
            qkv, w_qkv_dw, qkvd, vbf, total, 3 * EMB_);
    }

    // 4. q,k -> normalized bf16 (temp folded into q)
    headnorm_kernel<<<dim3(28, 8, 2), 256, 0, stream>>>(qkvd, temp, qn, kn);

    // 5. fused attention partials (JC=8, i-tile 32, dbuf exchange, pipelined K/V)
    attn_kernel<<<dim3(56, JC_, B_), 256, 0, stream>>>(qn, kn, vbf, w_attca, partY, partZ);

    // 6. combine partials -> outav (bf16)
    combine_kernel<<<3584, 256, 0, stream>>>(partY, partZ, outav);

    // 7. proj (B is bf16)
    gemm_kernel<false, false, true><<<dim3(14, 14, 2), 256, 0, stream>>>(
        w_proj, outav, outproj, TOK_, S_, EMB_, (long)EMB_ * S_, (long)TOK_ * S_,
        nullptr, nullptr, nullptr, nullptr);

    // 8. residual + LN2 + GDFN pin (bf16 x2, bf16 hbuf)
    resid_pin_kernel<<<dim3(7, B_ * N_), 256, 0, stream>>>(
        buffer, outproj, ln2_g, ln2_b, w_pin, x2, hbuf);

    // 9. fused GDFN tail
    gdfn_kernel<<<dim3(4, B_ * N_), 448, 0, stream>>>(hbuf, w_dw, w_pout, x2, out);
}